// Round 6
// baseline (384.201 us; speedup 1.0000x reference)
//
#include <hip/hip_runtime.h>

#define NN 100000
#define NE 1200000
#define NG 8
#define DIM 64
#define SCAN_BS 256
#define NB ((NN + SCAN_BS - 1) / SCAN_BS)  // 391
#define TILE 128
#define COLCAP (NE + 3 * NN)  // max padded CSR slots

// ---- degree histograms ----
__global__ void degree_kernel(const int* __restrict__ esrc, const int* __restrict__ edst,
                              int* __restrict__ outdeg, int* __restrict__ indeg, int E) {
  int i = blockIdx.x * blockDim.x + threadIdx.x;
  int st = gridDim.x * blockDim.x;
  for (; i < E; i += st) {
    atomicAdd(&outdeg[esrc[i]], 1);
    atomicAdd(&indeg[edst[i]], 1);
  }
}

// ---- xs = features * rsqrt(max(outdeg,1)), float4 per thread ----
__global__ void prescale_kernel(const float* __restrict__ f, const int* __restrict__ outdeg,
                                float* __restrict__ xs, int N) {
  int i = blockIdx.x * blockDim.x + threadIdx.x;
  if (i < N * 16) {
    int n = i >> 4;
    float sn = rsqrtf(fmaxf((float)outdeg[n], 1.0f));
    float4 v = ((const float4*)f)[i];
    v.x *= sn; v.y *= sn; v.z *= sn; v.w *= sn;
    ((float4*)xs)[i] = v;
  }
}

// ---- exclusive scan of ceil4(indeg) -> rp2 (3 kernels); also writes rp2[N] ----
__global__ __launch_bounds__(SCAN_BS) void scan1_kernel(const int* __restrict__ indeg,
                                                        int* __restrict__ rp2,
                                                        int* __restrict__ bsum, int N) {
  __shared__ int t[SCAN_BS];
  int i = blockIdx.x * SCAN_BS + threadIdx.x;
  int v = (i < N) ? ((indeg[i] + 3) & ~3) : 0;
  t[threadIdx.x] = v;
  __syncthreads();
  for (int off = 1; off < SCAN_BS; off <<= 1) {
    int u = (threadIdx.x >= off) ? t[threadIdx.x - off] : 0;
    __syncthreads();
    t[threadIdx.x] += u;
    __syncthreads();
  }
  if (i < N) rp2[i] = t[threadIdx.x] - v;
  if (i == N - 1) rp2[N] = t[threadIdx.x];
  if (threadIdx.x == SCAN_BS - 1) bsum[blockIdx.x] = t[threadIdx.x];
}

__global__ __launch_bounds__(512) void scan2_kernel(const int* __restrict__ bsum,
                                                    int* __restrict__ boff, int nb) {
  __shared__ int t[512];
  int v = ((int)threadIdx.x < nb) ? bsum[threadIdx.x] : 0;
  t[threadIdx.x] = v;
  __syncthreads();
  for (int off = 1; off < 512; off <<= 1) {
    int u = (threadIdx.x >= off) ? t[threadIdx.x - off] : 0;
    __syncthreads();
    t[threadIdx.x] += u;
    __syncthreads();
  }
  boff[threadIdx.x] = t[threadIdx.x] - v;
}

__global__ __launch_bounds__(SCAN_BS) void scan3_kernel(int* __restrict__ rp2,
                                                        const int* __restrict__ boff, int N) {
  int i = blockIdx.x * SCAN_BS + threadIdx.x;
  if (i < N) rp2[i] += boff[blockIdx.x];
  if (i == N - 1) rp2[N] += boff[blockIdx.x];
}

// ---- init col with NN (zero-row index) so pad slots are inherent ----
__global__ void colinit_kernel(int4* __restrict__ col4, int n4) {
  int i = blockIdx.x * blockDim.x + threadIdx.x;
  int st = gridDim.x * blockDim.x;
  for (; i < n4; i += st) col4[i] = make_int4(NN, NN, NN, NN);
}

// ---- fill CSR col (aligned base) ----
__global__ void fill_kernel(const int* __restrict__ esrc, const int* __restrict__ edst,
                            const int* __restrict__ rp2, int* __restrict__ cnt,
                            int* __restrict__ col, int E) {
  int i = blockIdx.x * blockDim.x + threadIdx.x;
  int st = gridDim.x * blockDim.x;
  for (; i < E; i += st) {
    int d = edst[i];
    int p = atomicAdd(&cnt[d], 1);
    col[rp2[d] + p] = esrc[i];
  }
}

// ---- gather: y[n] = rsqrt(max(indeg,1)) * sum_{slots} xs[col], 4 nodes/wave, no LDS/shfl ----
__global__ __launch_bounds__(256, 8) void gather_kernel(
    const float* __restrict__ xs, const int* __restrict__ indeg,
    const int* __restrict__ rp2, const int* __restrict__ col,
    float* __restrict__ y, int N) {
  const int lane = threadIdx.x & 63;
  const int wid = threadIdx.x >> 6;
  const int g = lane >> 4;
  const int t4 = (lane & 15) << 2;
  const int waveId = blockIdx.x * 4 + wid;
  const int stride4 = gridDim.x * 16;

  for (int n4 = waveId * 4; n4 < N; n4 += stride4) {
    int n = n4 + g;
    bool valid = n < N;
    int nc = valid ? n : 0;
    int base = rp2[nc];
    int end = rp2[nc + 1];
    float4 acc = make_float4(0.f, 0.f, 0.f, 0.f);
    for (int p = base; p < end; p += 4) {
      int4 cs = *(const int4*)(col + p);  // 16B-aligned, group-uniform
      float4 v0 = *(const float4*)(xs + (size_t)cs.x * DIM + t4);
      float4 v1 = *(const float4*)(xs + (size_t)cs.y * DIM + t4);
      float4 v2 = *(const float4*)(xs + (size_t)cs.z * DIM + t4);
      float4 v3 = *(const float4*)(xs + (size_t)cs.w * DIM + t4);
      acc.x += (v0.x + v1.x) + (v2.x + v3.x);
      acc.y += (v0.y + v1.y) + (v2.y + v3.y);
      acc.z += (v0.z + v1.z) + (v2.z + v3.z);
      acc.w += (v0.w + v1.w) + (v2.w + v3.w);
    }
    if (valid) {
      float dn = rsqrtf(fmaxf((float)indeg[n], 1.0f));
      acc.x *= dn; acc.y *= dn; acc.z *= dn; acc.w *= dn;
      *(float4*)(y + (size_t)n * DIM + t4) = acc;
    }
  }
}

// ---- MLP: out = relu(y @ W + b); POOL=0: in-place write *snorm; POOL=1: fused graph pooling ----
template <int POOL>
__global__ __launch_bounds__(256) void mlp_kernel(
    float* __restrict__ Y, const int* __restrict__ outdeg,
    const float* __restrict__ W, const float* __restrict__ b,
    const int* __restrict__ gid, float* __restrict__ gsum, float* __restrict__ gcnt, int N) {
  __shared__ float Xl[TILE][DIM + 1];
  __shared__ float Wl[DIM][DIM];
  __shared__ float bl[DIM];
  __shared__ float lsum[NG * DIM];
  __shared__ float lcnt[NG];
  const int t = threadIdx.x;
  const int nb = blockIdx.x * TILE;

  for (int i = t; i < DIM * DIM / 4; i += 256)
    ((float4*)&Wl[0][0])[i] = ((const float4*)W)[i];
  if (t < DIM / 4) ((float4*)bl)[t] = ((const float4*)b)[t];
#pragma unroll
  for (int r = 0; r < 8; ++r) {
    int i = t + r * 256;  // f4 idx in tile
    int node = i >> 4, c4 = (i & 15) << 2;
    int n = nb + node;
    float4 v = make_float4(0.f, 0.f, 0.f, 0.f);
    if (n < N) v = *(const float4*)(Y + (size_t)n * DIM + c4);
    *(float4*)&Xl[node][c4] = v;
  }
  if (POOL) {
    for (int i = t; i < NG * DIM; i += 256) lsum[i] = 0.0f;
    if (t < NG) lcnt[t] = 0.0f;
  }
  __syncthreads();

  const int node = t & (TILE - 1);
  const int j0 = (t >> 7) << 5;  // 0 or 32
  float acc[32];
#pragma unroll
  for (int u = 0; u < 8; ++u) {
    float4 bb = *(const float4*)&bl[j0 + u * 4];
    acc[u * 4 + 0] = bb.x; acc[u * 4 + 1] = bb.y;
    acc[u * 4 + 2] = bb.z; acc[u * 4 + 3] = bb.w;
  }
  for (int k = 0; k < DIM; k += 4) {
    float4 a4 = *(const float4*)&Xl[node][k];
    float a[4] = {a4.x, a4.y, a4.z, a4.w};
#pragma unroll
    for (int kk = 0; kk < 4; ++kk) {
      float ak = a[kk];
#pragma unroll
      for (int u = 0; u < 8; ++u) {
        float4 w = *(const float4*)&Wl[k + kk][j0 + u * 4];
        acc[u * 4 + 0] = fmaf(ak, w.x, acc[u * 4 + 0]);
        acc[u * 4 + 1] = fmaf(ak, w.y, acc[u * 4 + 1]);
        acc[u * 4 + 2] = fmaf(ak, w.z, acc[u * 4 + 2]);
        acc[u * 4 + 3] = fmaf(ak, w.w, acc[u * 4 + 3]);
      }
    }
  }
#pragma unroll
  for (int u = 0; u < 32; ++u) acc[u] = fmaxf(acc[u], 0.0f);
  __syncthreads();  // everyone done reading Xl
#pragma unroll
  for (int u = 0; u < 8; ++u)
    *(float4*)&Xl[node][j0 + u * 4] = make_float4(acc[u * 4], acc[u * 4 + 1], acc[u * 4 + 2], acc[u * 4 + 3]);
  __syncthreads();

  if (POOL) {
    for (int i = t; i < TILE * DIM; i += 256) {
      int nd = i >> 6, d = i & 63;
      int n = nb + nd;
      if (n < N) atomicAdd(&lsum[gid[n] * DIM + d], Xl[nd][d]);
    }
    for (int i = t; i < TILE; i += 256)
      if (nb + i < N) atomicAdd(&lcnt[gid[nb + i]], 1.0f);
    __syncthreads();
    for (int i = t; i < NG * DIM; i += 256) atomicAdd(&gsum[i], lsum[i]);
    if (t < NG) atomicAdd(&gcnt[t], lcnt[t]);
  } else {
#pragma unroll
    for (int r = 0; r < 8; ++r) {
      int i = t + r * 256;
      int nd = i >> 4, c4 = (i & 15) << 2;
      int n = nb + nd;
      if (n < N) {
        float sn = rsqrtf(fmaxf((float)outdeg[n], 1.0f));
        float4 v = *(const float4*)&Xl[nd][c4];
        v.x *= sn; v.y *= sn; v.z *= sn; v.w *= sn;
        *(float4*)(Y + (size_t)n * DIM + c4) = v;
      }
    }
  }
}

// ---- head ----
__global__ void final_kernel(const float* __restrict__ gsum, const float* __restrict__ gcnt,
                             const float* __restrict__ Wp, const float* __restrict__ bp,
                             float* __restrict__ out) {
  int lane = threadIdx.x;  // 64
#pragma unroll
  for (int g = 0; g < NG; ++g) {
    float inv = 1.0f / fmaxf(gcnt[g], 1.0f);
    float hv = gsum[g * DIM + lane] * inv;
#pragma unroll
    for (int c = 0; c < 2; ++c) {
      float p = hv * Wp[lane * 2 + c];
      for (int off = 32; off; off >>= 1) p += __shfl_down(p, off, 64);
      if (lane == 0) out[g * 2 + c] = p + bp[c];
    }
  }
}

extern "C" void kernel_launch(void* const* d_in, const int* in_sizes, int n_in,
                              void* d_out, int out_size, void* d_ws, size_t ws_size,
                              hipStream_t stream) {
  const float* features = (const float*)d_in[0];
  const float* W1 = (const float*)d_in[1];
  const float* b1 = (const float*)d_in[2];
  const float* W2 = (const float*)d_in[3];
  const float* b2 = (const float*)d_in[4];
  const float* Wp = (const float*)d_in[5];
  const float* bp = (const float*)d_in[6];
  const int* esrc = (const int*)d_in[7];
  const int* edst = (const int*)d_in[8];
  const int* gid = (const int*)d_in[9];
  float* out = (float*)d_out;

  const int N = NN, E = NE;

  // 64B-aligned workspace cursor (units: floats/words)
  float* base = (float*)d_ws;
  size_t off = 0;
  auto alloc = [&](size_t nwords) { size_t r = off; off = (off + nwords + 15) & ~(size_t)15; return r; };

  int* outdeg = (int*)(base + alloc(N));
  int* indeg  = (int*)(base + alloc(N));
  int* cnt    = (int*)(base + alloc(N));
  float* gsum = base + alloc(NG * DIM);
  float* gcnt = base + alloc(NG);
  size_t zeroWords = off;                      // everything above gets zeroed
  int* rp2   = (int*)(base + alloc(N + 1));
  int* bsum  = (int*)(base + alloc(512));
  int* boff  = (int*)(base + alloc(512));
  int* col   = (int*)(base + alloc(COLCAP));
  float* xs  = base + alloc((size_t)(N + 1) * DIM);  // prescaled feats; later y2; row N = zero
  float* B   = base + alloc((size_t)(N + 1) * DIM);  // y1 -> h1*snorm in place; row N = zero

  hipMemsetAsync(d_ws, 0, zeroWords * sizeof(float), stream);
  hipMemsetAsync(xs + (size_t)N * DIM, 0, DIM * sizeof(float), stream);
  hipMemsetAsync(B + (size_t)N * DIM, 0, DIM * sizeof(float), stream);

  degree_kernel<<<2048, 256, 0, stream>>>(esrc, edst, outdeg, indeg, E);
  prescale_kernel<<<(N * 16 + 255) / 256, 256, 0, stream>>>(features, outdeg, xs, N);

  scan1_kernel<<<NB, SCAN_BS, 0, stream>>>(indeg, rp2, bsum, N);
  scan2_kernel<<<1, 512, 0, stream>>>(bsum, boff, NB);
  scan3_kernel<<<NB, SCAN_BS, 0, stream>>>(rp2, boff, N);

  colinit_kernel<<<1465, 256, 0, stream>>>((int4*)col, COLCAP / 4);
  fill_kernel<<<2048, 256, 0, stream>>>(esrc, edst, rp2, cnt, col, E);

  // layer 1
  gather_kernel<<<2048, 256, 0, stream>>>(xs, indeg, rp2, col, B, N);
  mlp_kernel<0><<<(N + TILE - 1) / TILE, 256, 0, stream>>>(B, outdeg, W1, b1, gid, gsum, gcnt, N);
  // layer 2 (gather into xs buffer; pooling fused into MLP)
  gather_kernel<<<2048, 256, 0, stream>>>(B, indeg, rp2, col, xs, N);
  mlp_kernel<1><<<(N + TILE - 1) / TILE, 256, 0, stream>>>(xs, outdeg, W2, b2, gid, gsum, gcnt, N);

  final_kernel<<<1, 64, 0, stream>>>(gsum, gcnt, Wp, bp, out);
}